// Round 2
// baseline (492.288 us; speedup 1.0000x reference)
//
#include <hip/hip_runtime.h>
#include <hip/hip_bf16.h>

#define BB 64
#define TT 2048
#define D_ENC 512
#define D_RNN 1024
#define D_ATT 128
#define NF 32
#define KW 31

__device__ __forceinline__ float fast_tanh(float x) {
    // tanh(x) = 1 - 2/(exp(2x)+1); exact at saturation (exp->0 or inf)
    float e = __expf(2.0f * x);
    return 1.0f - __fdividef(2.0f, e + 1.0f);
}

// ---------------------------------------------------------------------------
// K1: pq[b][a] = dot(hidden[b,:], query_w[a,:])   (B x 128, K=1024)
// grid (B, 32) x 256 threads; one wave per output element.
// ---------------------------------------------------------------------------
__global__ __launch_bounds__(256) void pq_kernel(
    const float* __restrict__ hid, const float* __restrict__ qw,
    float* __restrict__ pq)
{
    int b = blockIdx.x;
    int wave = threadIdx.x >> 6, lane = threadIdx.x & 63;
    int a = blockIdx.y * 4 + wave;
    const float* hrow = hid + (size_t)b * D_RNN;
    const float* qrow = qw + (size_t)a * D_RNN;
    float acc = 0.f;
#pragma unroll
    for (int j = 0; j < 4; ++j) {
        int k = (j * 64 + lane) * 4;
        float4 h = *(const float4*)(hrow + k);
        float4 q = *(const float4*)(qrow + k);
        acc += h.x * q.x + h.y * q.y + h.z * q.z + h.w * q.w;
    }
#pragma unroll
    for (int off = 32; off; off >>= 1) acc += __shfl_xor(acc, off, 64);
    if (lane == 0) pq[b * D_ATT + a] = acc;
}

// ---------------------------------------------------------------------------
// K2: fused location-conv -> dense(NF->128) -> +pq +processed_memory -> tanh
//     -> dot(value_w) -> alignment[b][t]   (pre-softmax, mask applied)
// grid (B, T/128) x 256 threads. LDS: aw window (1.3KB) + loc feats (16KB).
// Conv weights & loc_dense rows live in registers; inner loops are
// register-FMA + broadcast LDS reads only.
// ---------------------------------------------------------------------------
__global__ __launch_bounds__(256) void align_kernel(
    const float* __restrict__ pm,          // (B,T,128)
    const float* __restrict__ awcat,       // (B,2,T)
    const unsigned char* __restrict__ mask,// (B,T) bool (all-false in test)
    const float* __restrict__ convw,       // (NF,2,KW)
    const float* __restrict__ ldw,         // (D_ATT,NF)
    const float* __restrict__ vw,          // (128)
    const float* __restrict__ pq,          // (B,128)
    float* __restrict__ align_out)         // (B,T)
{
    __shared__ float s_aw[2 * 160];
    __shared__ float s_loc[128 * NF];

    int b = blockIdx.x;
    int t0 = blockIdx.y * 128;
    int tid = threadIdx.x;

    // stage aw_cat window [t0-15, t0+144] with zero pad.
    // NOTE: 320 entries, 256 threads -> strided loop (bug fix vs R1: the
    // `if (tid < 320)` version left channel-1 entries 96..159 as stale LDS).
    for (int i = tid; i < 320; i += 256) {
        int c = i / 160, j = i % 160;
        int tg = t0 - 15 + j;
        float v = 0.f;
        if (tg >= 0 && tg < TT) v = awcat[((size_t)b * 2 + c) * TT + tg];
        s_aw[c * 160 + j] = v;
    }
    __syncthreads();

    // ---- phase 1: conv1d(2->NF, k=31, same).  thread: f = tid&31 owns one
    // filter; sliding window of 4 consecutive t's keeps taps in registers.
    {
        int f = tid & 31, g = tid >> 5;   // g in 0..7 owns t in [16g,16g+16)
        float w[2 * KW];
#pragma unroll
        for (int j = 0; j < 2 * KW; ++j) w[j] = convw[f * 2 * KW + j];
#pragma unroll
        for (int p = 0; p < 4; ++p) {
            int tb = g * 16 + p * 4;
            float a0 = 0.f, a1 = 0.f, a2 = 0.f, a3 = 0.f;
#pragma unroll
            for (int c = 0; c < 2; ++c) {
                float x[34];
#pragma unroll
                for (int j = 0; j < 34; ++j) x[j] = s_aw[c * 160 + tb + j];
#pragma unroll
                for (int k = 0; k < KW; ++k) {
                    float wk = w[c * KW + k];
                    a0 += x[k] * wk; a1 += x[k + 1] * wk;
                    a2 += x[k + 2] * wk; a3 += x[k + 3] * wk;
                }
            }
            s_loc[(tb + 0) * NF + f] = a0;
            s_loc[(tb + 1) * NF + f] = a1;
            s_loc[(tb + 2) * NF + f] = a2;
            s_loc[(tb + 3) * NF + f] = a3;
        }
    }
    __syncthreads();

    // ---- phase 2: energies + alignment. wave handles 32 t's; lane = a and
    // a+64; loc_dense rows preloaded to registers (16KB read/wave from L2).
    int wave = tid >> 6, lane = tid & 63;
    float pq0 = pq[b * 128 + lane], pq1 = pq[b * 128 + 64 + lane];
    float vw0 = vw[lane], vw1 = vw[64 + lane];
    float4 lA[8], lB[8];
#pragma unroll
    for (int f4 = 0; f4 < 8; ++f4) {
        lA[f4] = *(const float4*)(ldw + lane * NF + f4 * 4);
        lB[f4] = *(const float4*)(ldw + (64 + lane) * NF + f4 * 4);
    }
    const float* pmb = pm + ((size_t)b * TT + t0) * 128;
    for (int i = 0; i < 32; ++i) {
        int t = wave * 32 + i;
        float pm0 = pmb[(size_t)t * 128 + lane];
        float pm1 = pmb[(size_t)t * 128 + 64 + lane];
        float dA = 0.f, dB = 0.f;
#pragma unroll
        for (int f4 = 0; f4 < 8; ++f4) {
            float4 lv = *(const float4*)&s_loc[t * NF + f4 * 4];
            dA += lv.x * lA[f4].x + lv.y * lA[f4].y + lv.z * lA[f4].z + lv.w * lA[f4].w;
            dB += lv.x * lB[f4].x + lv.y * lB[f4].y + lv.z * lB[f4].z + lv.w * lB[f4].w;
        }
        float eA = fast_tanh(pq0 + pm0 + dA);
        float eB = fast_tanh(pq1 + pm1 + dB);
        float al = vw0 * eA + vw1 * eB;
#pragma unroll
        for (int off = 32; off; off >>= 1) al += __shfl_xor(al, off, 64);
        if (lane == 0) {
            int tt = t0 + t;
            bool m = mask[(size_t)b * TT + tt] != 0;
            align_out[(size_t)b * TT + tt] = m ? -__builtin_inff() : al;
        }
    }
}

// ---------------------------------------------------------------------------
// K3: softmax over T per batch row, in place on the weights region of d_out.
// ---------------------------------------------------------------------------
__global__ __launch_bounds__(256) void softmax_kernel(float* __restrict__ wts)
{
    int b = blockIdx.x;
    int tid = threadIdx.x;
    float* row = wts + (size_t)b * TT;
    float v[8];
    float mx = -__builtin_inff();
#pragma unroll
    for (int i = 0; i < 8; ++i) { v[i] = row[tid + i * 256]; mx = fmaxf(mx, v[i]); }
    __shared__ float s_red[8];
    int wave = tid >> 6, lane = tid & 63;
#pragma unroll
    for (int off = 32; off; off >>= 1) mx = fmaxf(mx, __shfl_xor(mx, off, 64));
    if (lane == 0) s_red[wave] = mx;
    __syncthreads();
    mx = fmaxf(fmaxf(s_red[0], s_red[1]), fmaxf(s_red[2], s_red[3]));
    float sum = 0.f;
#pragma unroll
    for (int i = 0; i < 8; ++i) { v[i] = __expf(v[i] - mx); sum += v[i]; }
#pragma unroll
    for (int off = 32; off; off >>= 1) sum += __shfl_xor(sum, off, 64);
    if (lane == 0) s_red[4 + wave] = sum;
    __syncthreads();
    sum = s_red[4] + s_red[5] + s_red[6] + s_red[7];
    float inv = __fdividef(1.0f, sum);
#pragma unroll
    for (int i = 0; i < 8; ++i) row[tid + i * 256] = v[i] * inv;
}

// ---------------------------------------------------------------------------
// K4: context[b][d] = sum_t w[b][t] * memory[b][t][d].  grid (B,16), each
// block reduces a 128-t chunk; float4 columns per lane; atomicAdd into the
// zeroed context region.  Streams the 268MB `memory` tensor once.
// ---------------------------------------------------------------------------
__global__ __launch_bounds__(256) void ctx_kernel(
    const float* __restrict__ mem, const float* __restrict__ wts,
    float* __restrict__ out)
{
    int b = blockIdx.x, c = blockIdx.y;
    int tid = threadIdx.x;
    int d4 = tid & 127;    // float4 column
    int th = tid >> 7;     // t-parity
    int t0 = c * 128;
    const float* wrow = wts + (size_t)b * TT + t0;
    const float4* mrow = (const float4*)(mem + ((size_t)b * TT + t0) * D_ENC);
    float4 acc = {0.f, 0.f, 0.f, 0.f};
    for (int i = th; i < 128; i += 2) {
        float w = wrow[i];
        float4 m = mrow[(size_t)i * 128 + d4];
        acc.x += w * m.x; acc.y += w * m.y; acc.z += w * m.z; acc.w += w * m.w;
    }
    __shared__ float4 s_p[128];
    if (th == 1) s_p[d4] = acc;
    __syncthreads();
    if (th == 0) {
        float4 o = s_p[d4];
        float* dst = out + (size_t)b * D_ENC + d4 * 4;
        atomicAdd(dst + 0, acc.x + o.x);
        atomicAdd(dst + 1, acc.y + o.y);
        atomicAdd(dst + 2, acc.z + o.z);
        atomicAdd(dst + 3, acc.w + o.w);
    }
}

extern "C" void kernel_launch(void* const* d_in, const int* in_sizes, int n_in,
                              void* d_out, int out_size, void* d_ws, size_t ws_size,
                              hipStream_t stream)
{
    const float* hid  = (const float*)d_in[0];
    const float* mem  = (const float*)d_in[1];
    const float* pm   = (const float*)d_in[2];
    const float* aw   = (const float*)d_in[3];
    const unsigned char* mask = (const unsigned char*)d_in[4];
    const float* qw   = (const float*)d_in[5];
    const float* vw   = (const float*)d_in[6];
    const float* cw   = (const float*)d_in[7];
    const float* ldw  = (const float*)d_in[8];

    float* out = (float*)d_out;
    float* ctx = out;                         // (B, D_ENC) first in tuple
    float* wts = out + BB * D_ENC;            // (B, T) second
    float* pq  = (float*)d_ws;                // (B, D_ATT) scratch

    hipMemsetAsync(ctx, 0, (size_t)BB * D_ENC * sizeof(float), stream);
    pq_kernel<<<dim3(BB, 32), 256, 0, stream>>>(hid, qw, pq);
    align_kernel<<<dim3(BB, TT / 128), 256, 0, stream>>>(pm, aw, mask, cw, ldw, vw, pq, wts);
    softmax_kernel<<<BB, 256, 0, stream>>>(wts);
    ctx_kernel<<<dim3(BB, 16), 256, 0, stream>>>(mem, wts, ctx);
}